// Round 7
// baseline (184.974 us; speedup 1.0000x reference)
//
#include <hip/hip_runtime.h>

// Problem constants (from reference)
#define M_PTS   16385     // int(65536*0.25)+1
#define K_NB    16
#define CIN_C   256
#define COUT_C  512
#define LN_EPS  1e-5f

#define OUT_XYZ_ELEMS (M_PTS * 3)                      // 49155
#define OUT_FEAT_OFF  OUT_XYZ_ELEMS
#define OUT_NOFF_IDX  (OUT_XYZ_ELEMS + M_PTS * COUT_C) // 8438275

#define NBLK 512          // 2 blocks per CU: independent barriers interleave
#define PPB  33           // ceil(16385/512) points per block

#define B_SCALE 16.0f     // lin_w pre-scale (keeps e4m3 out of subnormals)
#define B_INV   0.0625f

#define AROW_B 272        // A-tile row stride in BYTES (256 fp8 + 16 pad)

typedef __attribute__((ext_vector_type(4))) float f32x4;

// Barrier WITHOUT the compiler's vmcnt(0) drain: LDS writes must be visible
// (lgkmcnt(0)), but in-flight global prefetch loads may cross the barrier.
__device__ __forceinline__ void block_sync_lds() {
  asm volatile("s_waitcnt lgkmcnt(0)" ::: "memory");
  __builtin_amdgcn_s_barrier();
}

// Full-wave (64-lane) float sum on the VALU pipe via DPP — no DS-pipe ops.
__device__ __forceinline__ float wave_sum64(float v) {
  v += __int_as_float(__builtin_amdgcn_update_dpp(0, __float_as_int(v), 0xB1, 0xF, 0xF, false));
  v += __int_as_float(__builtin_amdgcn_update_dpp(0, __float_as_int(v), 0x4E, 0xF, 0xF, false));
  v += __int_as_float(__builtin_amdgcn_update_dpp(0, __float_as_int(v), 0x141, 0xF, 0xF, false));
  v += __int_as_float(__builtin_amdgcn_update_dpp(0, __float_as_int(v), 0x140, 0xF, 0xF, false));
  v += __int_as_float(__builtin_amdgcn_update_dpp(0, __float_as_int(v), 0x142, 0xA, 0xF, false));
  v += __int_as_float(__builtin_amdgcn_update_dpp(0, __float_as_int(v), 0x143, 0xC, 0xF, false));
  return __int_as_float(__builtin_amdgcn_readlane(__float_as_int(v), 63));
}

// LayerNorm the wave's 256-ch row (lane holds ch 4L..4L+3) and pack to 4 fp8.
__device__ __forceinline__ int ln_pack(float4 g, float4 nw, float4 nb) {
  float s1 = (g.x + g.y) + (g.z + g.w);
  float s2 = g.x * g.x + g.y * g.y + g.z * g.z + g.w * g.w;
  float S1 = wave_sum64(s1);
  float S2 = wave_sum64(s2);
  float mu  = S1 * (1.0f / 256.0f);
  float var = fmaf(-mu, mu, S2 * (1.0f / 256.0f));
  float rs  = rsqrtf(var + LN_EPS);
  float a = fmaf((g.x - mu) * rs, nw.x, nb.x);
  float b = fmaf((g.y - mu) * rs, nw.y, nb.y);
  float c = fmaf((g.z - mu) * rs, nw.z, nb.z);
  float d = fmaf((g.w - mu) * rs, nw.w, nb.w);
  int v = __builtin_amdgcn_cvt_pk_fp8_f32(a, b, 0, false);   // bytes 0,1
  v = __builtin_amdgcn_cvt_pk_fp8_f32(c, d, v, true);        // bytes 2,3
  return v;
}

// Prep: lin_w -> fp8(e4m3, x16) into ws, swizzled so each wave's persistent
// 32-col B load is coalesced 8B/lane (layout validated R6).
// Also: n_xyz gather and n_offset scalar.
__global__ void prep_kernel(const float* __restrict__ lin_w,
                            const float* __restrict__ xyz,
                            const int*   __restrict__ samp_idx,
                            const int*   __restrict__ offset,
                            unsigned char* __restrict__ lw8,
                            float*  __restrict__ out) {
  int tid = blockIdx.x * 256 + threadIdx.x;
  if (tid < COUT_C * CIN_C) {
    int o = tid >> 8;          // 0..511
    int c = tid & 255;         // 0..255
    int pos = ((o >> 5) << 13) | (((o >> 4) & 1) << 12) | ((c >> 5) << 9)
            | ((((c >> 3) & 3) * 16 + (o & 15)) << 3) | (c & 7);
    int pk = __builtin_amdgcn_cvt_pk_fp8_f32(lin_w[tid] * B_SCALE, 0.0f, 0, false);
    lw8[pos] = (unsigned char)(pk & 0xFF);
  }
  if (tid < OUT_XYZ_ELEMS) {
    int p = tid / 3;
    int c = tid - p * 3;
    out[tid] = xyz[(size_t)samp_idx[p] * 3 + c];
  }
  if (tid == 0) out[OUT_NOFF_IDX] = (float)(offset[0] / 4 + 1);
}

// GEMM one point's 16x256 fp8 A-tile against the wave's 32-col B registers,
// then maxpool over the 16 rows (layouts validated R6).
__device__ __forceinline__ void gemm_pool(const unsigned char* rowbase,
                                          const long Breg[8][2], int quad,
                                          float& v0, float& v1) {
  ulonglong2 q0 = *(const ulonglong2*)(rowbase + 0   + quad * 16);
  ulonglong2 q1 = *(const ulonglong2*)(rowbase + 64  + quad * 16);
  ulonglong2 q2 = *(const ulonglong2*)(rowbase + 128 + quad * 16);
  ulonglong2 q3 = *(const ulonglong2*)(rowbase + 192 + quad * 16);
  f32x4 a0 = {0.f, 0.f, 0.f, 0.f}, a1 = {0.f, 0.f, 0.f, 0.f};
  a0 = __builtin_amdgcn_mfma_f32_16x16x32_fp8_fp8((long)q0.x, Breg[0][0], a0, 0, 0, 0);
  a1 = __builtin_amdgcn_mfma_f32_16x16x32_fp8_fp8((long)q0.x, Breg[0][1], a1, 0, 0, 0);
  a0 = __builtin_amdgcn_mfma_f32_16x16x32_fp8_fp8((long)q0.y, Breg[1][0], a0, 0, 0, 0);
  a1 = __builtin_amdgcn_mfma_f32_16x16x32_fp8_fp8((long)q0.y, Breg[1][1], a1, 0, 0, 0);
  a0 = __builtin_amdgcn_mfma_f32_16x16x32_fp8_fp8((long)q1.x, Breg[2][0], a0, 0, 0, 0);
  a1 = __builtin_amdgcn_mfma_f32_16x16x32_fp8_fp8((long)q1.x, Breg[2][1], a1, 0, 0, 0);
  a0 = __builtin_amdgcn_mfma_f32_16x16x32_fp8_fp8((long)q1.y, Breg[3][0], a0, 0, 0, 0);
  a1 = __builtin_amdgcn_mfma_f32_16x16x32_fp8_fp8((long)q1.y, Breg[3][1], a1, 0, 0, 0);
  a0 = __builtin_amdgcn_mfma_f32_16x16x32_fp8_fp8((long)q2.x, Breg[4][0], a0, 0, 0, 0);
  a1 = __builtin_amdgcn_mfma_f32_16x16x32_fp8_fp8((long)q2.x, Breg[4][1], a1, 0, 0, 0);
  a0 = __builtin_amdgcn_mfma_f32_16x16x32_fp8_fp8((long)q2.y, Breg[5][0], a0, 0, 0, 0);
  a1 = __builtin_amdgcn_mfma_f32_16x16x32_fp8_fp8((long)q2.y, Breg[5][1], a1, 0, 0, 0);
  a0 = __builtin_amdgcn_mfma_f32_16x16x32_fp8_fp8((long)q3.x, Breg[6][0], a0, 0, 0, 0);
  a1 = __builtin_amdgcn_mfma_f32_16x16x32_fp8_fp8((long)q3.x, Breg[6][1], a1, 0, 0, 0);
  a0 = __builtin_amdgcn_mfma_f32_16x16x32_fp8_fp8((long)q3.y, Breg[7][0], a0, 0, 0, 0);
  a1 = __builtin_amdgcn_mfma_f32_16x16x32_fp8_fp8((long)q3.y, Breg[7][1], a1, 0, 0, 0);
  // D layout: col = lane&15, row = quad*4 + reg. Maxpool 16 rows.
  v0 = fmaxf(fmaxf(a0[0], a0[1]), fmaxf(a0[2], a0[3]));
  v0 = fmaxf(v0, __shfl_xor(v0, 16, 64));
  v0 = fmaxf(v0, __shfl_xor(v0, 32, 64));
  v1 = fmaxf(fmaxf(a1[0], a1[1]), fmaxf(a1[2], a1[3]));
  v1 = fmaxf(v1, __shfl_xor(v1, 16, 64));
  v1 = fmaxf(v1, __shfl_xor(v1, 32, 64));
}

// Fused main: block = 1024 threads = 16 waves, 2 points/iteration, 2 blocks/CU.
__global__ __launch_bounds__(1024, 4)
void td_main(const float*  __restrict__ feats,
             const float*  __restrict__ norm_w,
             const float*  __restrict__ norm_b,
             const unsigned char* __restrict__ lw8,
             const int*    __restrict__ knn,
             float* __restrict__ out) {
  __shared__ unsigned char A8[2][32 * AROW_B];   // 2 x 8704 B
  __shared__ int Kidx[PPB * K_NB];               // 2112 B -> total 19520 B

  const int tid  = threadIdx.x;
  const int lane = tid & 63;
  const int w    = tid >> 6;        // wave = neighbor row AND 32-col chunk
  const int quad = lane >> 4;
  const int lcol = lane & 15;

  const int pstart = blockIdx.x * PPB;
  const int npts   = min(pstart + PPB, M_PTS) - pstart;
  if (npts <= 0) return;            // tail blocks exit before any barrier

  // Stage this block's knn indices
  for (int i = tid; i < npts * K_NB; i += 1024)
    Kidx[i] = knn[pstart * K_NB + i];

  // Persistent fp8 B chunk: Breg[kk][g], 32 VGPRs, coalesced 8B/lane loads
  long Breg[8][2];
  {
    const unsigned char* base = lw8 + (w << 13) + lane * 8;
#pragma unroll
    for (int g = 0; g < 2; ++g)
#pragma unroll
      for (int kk = 0; kk < 8; ++kk) {
        Breg[kk][g] = *(const long*)(base + (g << 12) + (kk << 9));
        asm volatile("" : "+v"(Breg[kk][g]));   // opaque: cannot be re-sunk
      }
  }

  // LayerNorm weights for this lane's 4 channels
  const float4 nw = ((const float4*)norm_w)[lane];
  const float4 nb = ((const float4*)norm_b)[lane];

  // A-write byte offset within a row (validated R6): frag pairs b128-contiguous
  const int wdw = ((lane >> 4) << 6) + (((lane >> 1) & 3) << 4)
                + (lane & 8) + ((lane & 1) << 2);

  __syncthreads();                  // Kidx visible (full sync, once)

  // Preload pair 0 (rows w of points 0 and 1), 16B/lane coalesced
  float4 fa = ((const float4*)(feats + (size_t)Kidx[w] * CIN_C))[lane];
  float4 fb = ((const float4*)(feats +
               (size_t)Kidx[min(1, npts - 1) * K_NB + w] * CIN_C))[lane];

  const int nit = (npts + 1) >> 1;
  for (int it = 0; it < nit; ++it) {
    const int pa = 2 * it, pb = 2 * it + 1;

    // Prefetch pair it+1 (crosses the lgkm-only barrier un-drained)
    float4 na = fa, nb2 = fb;
    if (it + 1 < nit) {
      int qa = min(pa + 2, npts - 1), qb = min(pa + 3, npts - 1);
      na  = ((const float4*)(feats + (size_t)Kidx[qa * K_NB + w] * CIN_C))[lane];
      nb2 = ((const float4*)(feats + (size_t)Kidx[qb * K_NB + w] * CIN_C))[lane];
    }

    // LayerNorm + fp8-pack + LDS write: rows w (pt a) and 16+w (pt b)
    unsigned char* Ab = A8[it & 1];
    *(int*)(Ab + w * AROW_B + wdw)        = ln_pack(fa, nw, nb);
    *(int*)(Ab + (16 + w) * AROW_B + wdw) = ln_pack(fb, nw, nb);

    block_sync_lds();               // A visible; prefetch NOT drained

    // GEMM + maxpool, point a then point b
    float v0, v1;
    gemm_pool(Ab + lcol * AROW_B, Breg, quad, v0, v1);
    float* outa = out + OUT_FEAT_OFF + (size_t)(pstart + pa) * COUT_C + w * 32;
    if (quad < 2) outa[quad * 16 + lcol] = (quad ? v1 : v0) * B_INV;

    gemm_pool(Ab + (16 + lcol) * AROW_B, Breg, quad, v0, v1);
    if (pb < npts) {
      float* outb = out + OUT_FEAT_OFF + (size_t)(pstart + pb) * COUT_C + w * 32;
      if (quad < 2) outb[quad * 16 + lcol] = (quad ? v1 : v0) * B_INV;
    }
    // A[it&1] reuse at it+2 is ordered by the barrier at it+1.
    fa = na; fb = nb2;
  }
}

extern "C" void kernel_launch(void* const* d_in, const int* in_sizes, int n_in,
                              void* d_out, int out_size, void* d_ws, size_t ws_size,
                              hipStream_t stream) {
  const float* xyz      = (const float*)d_in[0];
  const float* feats    = (const float*)d_in[1];
  const float* norm_w   = (const float*)d_in[2];
  const float* norm_b   = (const float*)d_in[3];
  const float* lin_w    = (const float*)d_in[4];
  const int*   samp_idx = (const int*)d_in[5];
  const int*   knn      = (const int*)d_in[6];
  const int*   offset   = (const int*)d_in[7];
  float* out = (float*)d_out;
  unsigned char* lw8 = (unsigned char*)d_ws;        // 512*256 = 128 KB fp8

  prep_kernel<<<512, 256, 0, stream>>>(lin_w, xyz, samp_idx, offset, lw8, out);

  td_main<<<NBLK, 1024, 0, stream>>>(feats, norm_w, norm_b, lw8, knn, out);
}